// Round 7
// baseline (134.616 us; speedup 1.0000x reference)
//
#include <hip/hip_runtime.h>

#define L2E 1.4426950408889634f
#define LN2 0.6931471805599453f

typedef float f32x16 __attribute__((ext_vector_type(16)));
typedef float f32x2  __attribute__((ext_vector_type(2)));
typedef short bf16x8 __attribute__((ext_vector_type(8)));
typedef unsigned int u32x4 __attribute__((ext_vector_type(4)));

__device__ __forceinline__ float dexp2(float x) { return __builtin_amdgcn_exp2f(x); }
__device__ __forceinline__ float dlog2(float x) { return __builtin_amdgcn_logf(x); }

// HW packed f32->2xbf16 (RNE). Inputs must be IR-produced VALU values
// (never raw MFMA accumulator regs) -- R3 post-mortem.
__device__ __forceinline__ unsigned cvtpk(float a, float b) {
    unsigned r;
    asm("v_cvt_pk_bf16_f32 %0, %1, %2" : "=v"(r) : "v"(a), "v"(b));
    return r;
}

// Software RNE pack (pure IR): for cold paths reading raw MFMA results.
__device__ __forceinline__ unsigned pkrne(float a, float b) {
    unsigned ua = __float_as_uint(a), ub = __float_as_uint(b);
    ua += 0x7FFFu + ((ua >> 16) & 1u);
    ub += 0x7FFFu + ((ub >> 16) & 1u);
    return __builtin_amdgcn_perm(ub, ua, 0x07060302u);
}

// CRF forward via exp-domain transfer matrices, C-form chain:
//   tau_t = E * (D_t * tau_{t-1}),  tau_0 = E[:,START]
// A-operand = E CONSTANT (bf16). D_t staged as fp8-e4m3 in a half-permuted
// layout so the per-step B-side row scale needs ONE broadcast ds_read_b128
// (R6 post-mortem: 4x ds_read_b128/step saturated the per-CU LDS unit).
__global__ __launch_bounds__(1024, 8) void crf_phase_kernel(
    const float* __restrict__ em,   // [512][2048][32]
    const float* __restrict__ tr,   // [32][32] transitions[tag][prev]
    const int*   __restrict__ tgs,  // [512][2048]
    float*       __restrict__ ws)   // [512] per-batch nll
{
    __shared__ float s_tr[1024];                 // 4 KB
    __shared__ unsigned short s_mat[16 * 1024];  // 32 KB [chunk][col][row] bf16
    __shared__ unsigned s_d8[16 * 64];           // 4 KB: wave -> 8 slots x 8 dwords (32 fp8)
    __shared__ float s_vec[32];                  // phase-2 scratch
    __shared__ float s_base[16];
    __shared__ float s_gold[16];

    const int tid = threadIdx.x;
    const int b   = blockIdx.x;
    const int w   = tid >> 6;    // wave = chunk index 0..15
    const int l   = tid & 63;
    const int h   = l >> 5;
    const int q   = l & 31;

    s_tr[tid & 1023] = tr[tid & 1023];
    __syncthreads();

    // Constant A = E with pi'd columns (pi = swap bits 2<->3), bf16, packed once.
    unsigned ea[8];
#pragma unroll
    for (int j = 0; j < 8; ++j) {
        int k0  = 16 * (j >> 2) + 8 * h + 2 * (j & 3);
        int col = (k0 & ~12) | ((k0 & 4) << 1) | ((k0 & 8) >> 1);
        ea[j] = pkrne(dexp2(s_tr[q * 32 + col] * L2E),
                      dexp2(s_tr[q * 32 + col + 1] * L2E));
    }
    const bf16x8 A0 = __builtin_bit_cast(bf16x8, (u32x4){ea[0], ea[1], ea[2], ea[3]});
    const bf16x8 A1 = __builtin_bit_cast(bf16x8, (u32x4){ea[4], ea[5], ea[6], ea[7]});

    const float* ebase = em + ((size_t)b * 2048 + (size_t)w * 128) * 32;
    const int*   tgp   = tgs + (size_t)b * 2048;

    f32x16 acc;              // carried chunk product (f32, C/D layout)
    float  s_cur = 1.f;      // pending 2^-k rescale (applied at s==0/s==4 packs)
    int    k_pend = 0, sigma = 0;
    float  gold = 0.f;
    float4 r0, r1;
    int    tregC = 0, tlastC = 0, tregN = 0, tlastN = 0;

    // identity product (f32, C/D layout)
#pragma unroll
    for (int r = 0; r < 16; ++r)
        acc[r] = ((((r & 3) + 8 * (r >> 2) + 4 * h) == q) ? 1.f : 0.f);

    auto eload = [&](int blk) -> float4 {
        int bb2 = blk > 15 ? 15 : blk;
        return *(const float4*)(ebase + ((bb2 * 8 + (l >> 3)) * 32 + (l & 7) * 4));
    };
    auto tagload = [&](int cl, int& treg, int& tlast) {
        int c0 = w * 128 + cl * 64;
        int idx = c0 - 1 + l; if (idx < 0) idx = 0;
        treg  = tgp[idx];
        tlast = tgp[c0 + 63];
    };

    r0 = eload(0); r1 = eload(1);
    tagload(0, tregC, tlastC);

#pragma unroll 1
    for (int blk = 0; blk < 16; ++blk) {
        if ((blk & 7) == 0) {
            int cl = blk >> 3;           // 0 or 1
            int cg = w * 2 + cl;         // global 64-group index 0..31
            if (cl > 0) { tregC = tregN; tlastC = tlastN; }
            {   // gold transition terms for this 64-group
                int scur = __shfl(tregC, (l + 1) & 63, 64);
                int cur  = (l == 63) ? tlastC : scur;
                int prev = tregC;
                if (l == 0 && cg == 0) prev = 30;      // START
                gold += s_tr[cur * 32 + prev];
            }
            if (cl < 1) tagload(cl + 1, tregN, tlastN);
        }

        // ---- stage d_t = exp(e_t) as fp8, half-permuted; gold pick ----
        {
            int trel = (blk & 7) * 8 + (l >> 3);
            int tshf = __shfl(tregC, (trel + 1) & 63, 64);
            int tgt  = (trel == 63) ? tlastC : tshf;
            if ((tgt >> 2) == (l & 7)) {
                int sub = tgt & 3;
                float ev = sub == 0 ? r0.x : sub == 1 ? r0.y : sub == 2 ? r0.z : r0.w;
                gold += ev;
            }
            float4 dv;
            dv.x = dexp2(r0.x * L2E); dv.y = dexp2(r0.y * L2E);
            dv.z = dexp2(r0.z * L2E); dv.w = dexp2(r0.w * L2E);
            // pack 4 fp8 into one dword: bytes = d[tags 4c..4c+3], c = l&7
            unsigned u = (unsigned)__builtin_amdgcn_cvt_pk_fp8_f32(dv.x, dv.y, 0, false);
            u = (unsigned)__builtin_amdgcn_cvt_pk_fp8_f32(dv.z, dv.w, (int)u, true);
            int c = l & 7;
            // slot layout: [slot][h=c&1][dword m=c>>1]; dword m holds d[8m+4h..+3]
            s_d8[w * 64 + (l >> 3) * 8 + (c & 1) * 4 + (c >> 1)] = u;
        }
        r0 = r1; r1 = eload(blk + 2);

        const bool skiplast = (blk == 15) && (w == 15);  // global step 2048

        // ---- 8 steps: acc <- E * (d_t o (s*acc)) ; A constant ----
#pragma unroll
        for (int s = 0; s < 8; ++s) {
            if (s == 7 && skiplast) continue;
            // ONE broadcast b128: 16 fp8 d-values this half needs
            const u32x4 rv = *(const u32x4*)(s_d8 + w * 64 + s * 8 + h * 4);
            unsigned bbn[8];
            f32x16 zz;
#pragma unroll
            for (int q2 = 0; q2 < 4; ++q2) {
                f32x2 dlo = __builtin_amdgcn_cvt_pk_f32_fp8((int)rv[q2], false);
                f32x2 dhi = __builtin_amdgcn_cvt_pk_f32_fp8((int)rv[q2], true);
                f32x2 a0; a0.x = acc[4 * q2 + 0]; a0.y = acc[4 * q2 + 1];
                f32x2 a1; a1.x = acc[4 * q2 + 2]; a1.y = acc[4 * q2 + 3];
                f32x2 m0 = a0 * dlo;
                f32x2 m1 = a1 * dhi;
                if (s == 0 || s == 4) {
                    f32x2 sc; sc.x = s_cur; sc.y = s_cur;
                    m0 = m0 * sc; m1 = m1 * sc;
                }
                bbn[2 * q2]     = cvtpk(m0.x, m0.y);
                bbn[2 * q2 + 1] = cvtpk(m1.x, m1.y);
                // zero C built from acc (finite, nonneg -> exact +0; not
                // constant-foldable without fast-math, avoids 16-mov remat)
                zz[4 * q2 + 0] = acc[4 * q2 + 0] * 0.f;
                zz[4 * q2 + 1] = acc[4 * q2 + 1] * 0.f;
                zz[4 * q2 + 2] = acc[4 * q2 + 2] * 0.f;
                zz[4 * q2 + 3] = acc[4 * q2 + 3] * 0.f;
            }
            if (s == 0 || s == 4) sigma += k_pend;
            bf16x8 B0 = __builtin_bit_cast(bf16x8, (u32x4){bbn[0], bbn[1], bbn[2], bbn[3]});
            bf16x8 B1 = __builtin_bit_cast(bf16x8, (u32x4){bbn[4], bbn[5], bbn[6], bbn[7]});
            f32x16 t = __builtin_amdgcn_mfma_f32_32x32x16_bf16(A0, B0, zz, 0, 0, 0);
            acc = __builtin_amdgcn_mfma_f32_32x32x16_bf16(A1, B1, t, 0, 0, 0);
            if (s == 3 || s == 7) {
                unsigned eb = (__float_as_uint(acc[0]) >> 23) & 0xFF;
                unsigned ku = (unsigned)__builtin_amdgcn_readfirstlane((int)eb);
                k_pend = (int)ku - 127;
                s_cur = __uint_as_float((254u - ku) << 23);
            }
        }
    }

    // ---- store this wave's chunk matrix ----
#pragma unroll
    for (int p = 0; p < 8; ++p) {
        int rrow = ((2 * p) & 3) + 8 * ((2 * p) >> 2) + 4 * h;
        *(unsigned*)(s_mat + w * 1024 + q * 32 + rrow) =
            pkrne(acc[2 * p], acc[2 * p + 1]);
    }
    if (l == 0) s_base[w] = (float)sigma;

    // per-wave gold reduction
#pragma unroll
    for (int m = 1; m < 64; m <<= 1) gold += __shfl_xor(gold, m, 64);
    if (l == 0) s_gold[w] = gold;
    __syncthreads();

    // ---- phase 2: serial chain over 16 chunk matrices (lanes 0..31) ----
    if (tid < 32) {
        int i = tid;
        float x  = dexp2(s_tr[i * 32 + 30] * L2E);   // tau_0 = E[:,START]
        float xb = 0.f, bs = 0.f;
        for (int c = 0; c < 16; ++c) {
            s_vec[i] = x;
            float yv[32];
#pragma unroll
            for (int j = 0; j < 8; ++j) *(float4*)&yv[4 * j] = *(const float4*)&s_vec[4 * j];
            float a2 = 0.f;
#pragma unroll
            for (int j = 0; j < 32; ++j) {
                unsigned short uv = s_mat[c * 1024 + j * 32 + i];
                a2 += __uint_as_float((unsigned)uv << 16) * yv[j];
            }
            unsigned eb2 = (__float_as_uint(a2) >> 23) & 0xFF;
            int ku0 = __shfl((int)eb2, 0, 32);
            x  = a2 * __uint_as_float((unsigned)(254 - ku0) << 23);
            xb += (float)(ku0 - 127);
            bs += s_base[c];
        }
        // final: Z = sum_i exp(tr[STOP,i] + e_2048[i]) * tau_2047[i]
        float elast = em[((size_t)b * 2048 + 2047) * 32 + i];
        float wv = dexp2((s_tr[31 * 32 + i] + elast) * L2E);
        float sv = x * wv;
#pragma unroll
        for (int m2 = 1; m2 < 32; m2 <<= 1) sv += __shfl_xor(sv, m2, 32);
        float logZ = (xb + bs + dlog2(sv)) * LN2;
        if (i == 0) {
            float g = 0.f;
#pragma unroll
            for (int wv2 = 0; wv2 < 16; ++wv2) g += s_gold[wv2];
            g += s_tr[31 * 32 + tgp[2047]];   // STOP term
            ws[b] = logZ - g;
        }
    }
}

// Deterministic fixed-order reduction of the 512 per-batch values.
__global__ __launch_bounds__(64) void crf_reduce_kernel(
    const float* __restrict__ ws, float* __restrict__ out)
{
    int l = threadIdx.x;
    float s = 0.f;
#pragma unroll
    for (int k = 0; k < 8; ++k) s += ws[l + k * 64];
    s += __shfl_xor(s, 1, 64);
    s += __shfl_xor(s, 2, 64);
    s += __shfl_xor(s, 4, 64);
    s += __shfl_xor(s, 8, 64);
    s += __shfl_xor(s, 16, 64);
    s += __shfl_xor(s, 32, 64);
    if (l == 0) out[0] = s;
}

extern "C" void kernel_launch(void* const* d_in, const int* in_sizes, int n_in,
                              void* d_out, int out_size, void* d_ws, size_t ws_size,
                              hipStream_t stream)
{
    const float* em = (const float*)d_in[0];
    const float* tr = (const float*)d_in[1];
    const int*   tg = (const int*)d_in[2];
    float* ws  = (float*)d_ws;
    float* out = (float*)d_out;

    hipLaunchKernelGGL(crf_phase_kernel, dim3(512), dim3(1024), 0, stream, em, tr, tg, ws);
    hipLaunchKernelGGL(crf_reduce_kernel, dim3(1), dim3(64), 0, stream, ws, out);
}

// Round 8
// 107.072 us; speedup vs baseline: 1.2573x; 1.2573x over previous
//
#include <hip/hip_runtime.h>

#define L2E 1.4426950408889634f
#define LN2 0.6931471805599453f

typedef float f32x16 __attribute__((ext_vector_type(16)));
typedef float f32x2  __attribute__((ext_vector_type(2)));
typedef short bf16x8 __attribute__((ext_vector_type(8)));
typedef unsigned int u32x4 __attribute__((ext_vector_type(4)));

__device__ __forceinline__ float dexp2(float x) { return __builtin_amdgcn_exp2f(x); }
__device__ __forceinline__ float dlog2(float x) { return __builtin_amdgcn_logf(x); }

// HW packed f32->2xbf16 (RNE). Inputs must be IR-produced VALU values
// (never raw MFMA accumulator regs) -- R3 post-mortem.
__device__ __forceinline__ unsigned cvtpk(float a, float b) {
    unsigned r;
    asm("v_cvt_pk_bf16_f32 %0, %1, %2" : "=v"(r) : "v"(a), "v"(b));
    return r;
}

// Software RNE pack (pure IR): for cold paths reading raw MFMA results.
__device__ __forceinline__ unsigned pkrne(float a, float b) {
    unsigned ua = __float_as_uint(a), ub = __float_as_uint(b);
    ua += 0x7FFFu + ((ua >> 16) & 1u);
    ub += 0x7FFFu + ((ub >> 16) & 1u);
    return __builtin_amdgcn_perm(ub, ua, 0x07060302u);
}

// CRF forward via exp-domain transfer matrices, C-form chain:
//   tau_t = E * (D_t * tau_{t-1}),  tau_0 = E[:,START]
// A-operand = E CONSTANT (bf16). D_t staged as fp8-e4m3 half-permuted so the
// per-step row scale needs ONE broadcast ds_read_b128 (DS was ~83% busy with
// 4 reads/step). launch_bounds(1024,4): 128-VGPR budget -- R7's (1024,8)
// forced 64 VGPRs and spilled 10 MB to scratch (the R7 regression).
__global__ __launch_bounds__(1024, 4) void crf_phase_kernel(
    const float* __restrict__ em,   // [512][2048][32]
    const float* __restrict__ tr,   // [32][32] transitions[tag][prev]
    const int*   __restrict__ tgs,  // [512][2048]
    float*       __restrict__ ws)   // [512] per-batch nll
{
    __shared__ float s_tr[1024];                 // 4 KB
    __shared__ unsigned short s_mat[16 * 1024];  // 32 KB [chunk][col][row] bf16
    __shared__ unsigned s_d8[16 * 64];           // 4 KB: wave -> 8 slots x 8 dwords (32 fp8)
    __shared__ float s_vec[32];                  // phase-2 scratch
    __shared__ float s_base[16];
    __shared__ float s_gold[16];

    const int tid = threadIdx.x;
    const int b   = blockIdx.x;
    const int w   = tid >> 6;    // wave = chunk index 0..15
    const int l   = tid & 63;
    const int h   = l >> 5;
    const int q   = l & 31;

    s_tr[tid & 1023] = tr[tid & 1023];
    __syncthreads();

    // Constant A = E with pi'd columns (pi = swap bits 2<->3), bf16, packed once.
    unsigned ea[8];
#pragma unroll
    for (int j = 0; j < 8; ++j) {
        int k0  = 16 * (j >> 2) + 8 * h + 2 * (j & 3);
        int col = (k0 & ~12) | ((k0 & 4) << 1) | ((k0 & 8) >> 1);
        ea[j] = pkrne(dexp2(s_tr[q * 32 + col] * L2E),
                      dexp2(s_tr[q * 32 + col + 1] * L2E));
    }
    const bf16x8 A0 = __builtin_bit_cast(bf16x8, (u32x4){ea[0], ea[1], ea[2], ea[3]});
    const bf16x8 A1 = __builtin_bit_cast(bf16x8, (u32x4){ea[4], ea[5], ea[6], ea[7]});

    // Hoisted zero C-operand (R6-validated; R7's per-step acc*0 rebuild
    // caused the spill).
    f32x16 zro;
#pragma unroll
    for (int z = 0; z < 16; ++z) zro[z] = 0.f;

    const float* ebase = em + ((size_t)b * 2048 + (size_t)w * 128) * 32;
    const int*   tgp   = tgs + (size_t)b * 2048;

    f32x16 acc;              // carried chunk product (f32, C/D layout)
    float  s_cur = 1.f;      // pending 2^-k rescale (applied at s==0/s==4 packs)
    int    k_pend = 0, sigma = 0;
    float  gold = 0.f;
    float4 r0, r1;
    int    tregC = 0, tlastC = 0, tregN = 0, tlastN = 0;

    // identity product (f32, C/D layout)
#pragma unroll
    for (int r = 0; r < 16; ++r)
        acc[r] = ((((r & 3) + 8 * (r >> 2) + 4 * h) == q) ? 1.f : 0.f);

    auto eload = [&](int blk) -> float4 {
        int bb2 = blk > 15 ? 15 : blk;
        return *(const float4*)(ebase + ((bb2 * 8 + (l >> 3)) * 32 + (l & 7) * 4));
    };
    auto tagload = [&](int cl, int& treg, int& tlast) {
        int c0 = w * 128 + cl * 64;
        int idx = c0 - 1 + l; if (idx < 0) idx = 0;
        treg  = tgp[idx];
        tlast = tgp[c0 + 63];
    };

    r0 = eload(0); r1 = eload(1);
    tagload(0, tregC, tlastC);

#pragma unroll 1
    for (int blk = 0; blk < 16; ++blk) {
        if ((blk & 7) == 0) {
            int cl = blk >> 3;           // 0 or 1
            int cg = w * 2 + cl;         // global 64-group index 0..31
            if (cl > 0) { tregC = tregN; tlastC = tlastN; }
            {   // gold transition terms for this 64-group
                int scur = __shfl(tregC, (l + 1) & 63, 64);
                int cur  = (l == 63) ? tlastC : scur;
                int prev = tregC;
                if (l == 0 && cg == 0) prev = 30;      // START
                gold += s_tr[cur * 32 + prev];
            }
            if (cl < 1) tagload(cl + 1, tregN, tlastN);
        }

        // ---- stage d_t = exp(e_t) as fp8, half-permuted; gold pick ----
        {
            int trel = (blk & 7) * 8 + (l >> 3);
            int tshf = __shfl(tregC, (trel + 1) & 63, 64);
            int tgt  = (trel == 63) ? tlastC : tshf;
            if ((tgt >> 2) == (l & 7)) {
                int sub = tgt & 3;
                float ev = sub == 0 ? r0.x : sub == 1 ? r0.y : sub == 2 ? r0.z : r0.w;
                gold += ev;
            }
            float4 dv;
            dv.x = dexp2(r0.x * L2E); dv.y = dexp2(r0.y * L2E);
            dv.z = dexp2(r0.z * L2E); dv.w = dexp2(r0.w * L2E);
            // pack 4 fp8 into one dword: bytes = d[tags 4c..4c+3], c = l&7
            unsigned u = (unsigned)__builtin_amdgcn_cvt_pk_fp8_f32(dv.x, dv.y, 0, false);
            u = (unsigned)__builtin_amdgcn_cvt_pk_fp8_f32(dv.z, dv.w, (int)u, true);
            int c = l & 7;
            // slot layout: [slot][h=c&1][dword m=c>>1]; dword m holds d[8m+4h..+3]
            s_d8[w * 64 + (l >> 3) * 8 + (c & 1) * 4 + (c >> 1)] = u;
        }
        r0 = r1; r1 = eload(blk + 2);

        const bool skiplast = (blk == 15) && (w == 15);  // global step 2048

        // ---- 8 steps: acc <- E * (d_t o (s*acc)) ; A constant ----
#pragma unroll
        for (int s = 0; s < 8; ++s) {
            if (s == 7 && skiplast) continue;
            // ONE broadcast b128: 16 fp8 d-values this half needs
            const u32x4 rv = *(const u32x4*)(s_d8 + w * 64 + s * 8 + h * 4);
            unsigned bbn[8];
#pragma unroll
            for (int q2 = 0; q2 < 4; ++q2) {
                f32x2 dlo = __builtin_amdgcn_cvt_pk_f32_fp8((int)rv[q2], false);
                f32x2 dhi = __builtin_amdgcn_cvt_pk_f32_fp8((int)rv[q2], true);
                f32x2 a0; a0.x = acc[4 * q2 + 0]; a0.y = acc[4 * q2 + 1];
                f32x2 a1; a1.x = acc[4 * q2 + 2]; a1.y = acc[4 * q2 + 3];
                f32x2 m0 = a0 * dlo;
                f32x2 m1 = a1 * dhi;
                if (s == 0 || s == 4) {
                    f32x2 sc; sc.x = s_cur; sc.y = s_cur;
                    m0 = m0 * sc; m1 = m1 * sc;
                }
                bbn[2 * q2]     = cvtpk(m0.x, m0.y);
                bbn[2 * q2 + 1] = cvtpk(m1.x, m1.y);
            }
            if (s == 0 || s == 4) sigma += k_pend;
            bf16x8 B0 = __builtin_bit_cast(bf16x8, (u32x4){bbn[0], bbn[1], bbn[2], bbn[3]});
            bf16x8 B1 = __builtin_bit_cast(bf16x8, (u32x4){bbn[4], bbn[5], bbn[6], bbn[7]});
            f32x16 t = __builtin_amdgcn_mfma_f32_32x32x16_bf16(A0, B0, zro, 0, 0, 0);
            acc = __builtin_amdgcn_mfma_f32_32x32x16_bf16(A1, B1, t, 0, 0, 0);
            if (s == 3 || s == 7) {
                unsigned eb = (__float_as_uint(acc[0]) >> 23) & 0xFF;
                unsigned ku = (unsigned)__builtin_amdgcn_readfirstlane((int)eb);
                k_pend = (int)ku - 127;
                s_cur = __uint_as_float((254u - ku) << 23);
            }
        }
    }

    // ---- store this wave's chunk matrix ----
#pragma unroll
    for (int p = 0; p < 8; ++p) {
        int rrow = ((2 * p) & 3) + 8 * ((2 * p) >> 2) + 4 * h;
        *(unsigned*)(s_mat + w * 1024 + q * 32 + rrow) =
            pkrne(acc[2 * p], acc[2 * p + 1]);
    }
    if (l == 0) s_base[w] = (float)sigma;

    // per-wave gold reduction
#pragma unroll
    for (int m = 1; m < 64; m <<= 1) gold += __shfl_xor(gold, m, 64);
    if (l == 0) s_gold[w] = gold;
    __syncthreads();

    // ---- phase 2: serial chain over 16 chunk matrices (lanes 0..31) ----
    if (tid < 32) {
        int i = tid;
        float x  = dexp2(s_tr[i * 32 + 30] * L2E);   // tau_0 = E[:,START]
        float xb = 0.f, bs = 0.f;
        for (int c = 0; c < 16; ++c) {
            s_vec[i] = x;
            float yv[32];
#pragma unroll
            for (int j = 0; j < 8; ++j) *(float4*)&yv[4 * j] = *(const float4*)&s_vec[4 * j];
            float a2 = 0.f;
#pragma unroll
            for (int j = 0; j < 32; ++j) {
                unsigned short uv = s_mat[c * 1024 + j * 32 + i];
                a2 += __uint_as_float((unsigned)uv << 16) * yv[j];
            }
            unsigned eb2 = (__float_as_uint(a2) >> 23) & 0xFF;
            int ku0 = __shfl((int)eb2, 0, 32);
            x  = a2 * __uint_as_float((unsigned)(254 - ku0) << 23);
            xb += (float)(ku0 - 127);
            bs += s_base[c];
        }
        // final: Z = sum_i exp(tr[STOP,i] + e_2048[i]) * tau_2047[i]
        float elast = em[((size_t)b * 2048 + 2047) * 32 + i];
        float wv = dexp2((s_tr[31 * 32 + i] + elast) * L2E);
        float sv = x * wv;
#pragma unroll
        for (int m2 = 1; m2 < 32; m2 <<= 1) sv += __shfl_xor(sv, m2, 32);
        float logZ = (xb + bs + dlog2(sv)) * LN2;
        if (i == 0) {
            float g = 0.f;
#pragma unroll
            for (int wv2 = 0; wv2 < 16; ++wv2) g += s_gold[wv2];
            g += s_tr[31 * 32 + tgp[2047]];   // STOP term
            ws[b] = logZ - g;
        }
    }
}

// Deterministic fixed-order reduction of the 512 per-batch values.
__global__ __launch_bounds__(64) void crf_reduce_kernel(
    const float* __restrict__ ws, float* __restrict__ out)
{
    int l = threadIdx.x;
    float s = 0.f;
#pragma unroll
    for (int k = 0; k < 8; ++k) s += ws[l + k * 64];
    s += __shfl_xor(s, 1, 64);
    s += __shfl_xor(s, 2, 64);
    s += __shfl_xor(s, 4, 64);
    s += __shfl_xor(s, 8, 64);
    s += __shfl_xor(s, 16, 64);
    s += __shfl_xor(s, 32, 64);
    if (l == 0) out[0] = s;
}

extern "C" void kernel_launch(void* const* d_in, const int* in_sizes, int n_in,
                              void* d_out, int out_size, void* d_ws, size_t ws_size,
                              hipStream_t stream)
{
    const float* em = (const float*)d_in[0];
    const float* tr = (const float*)d_in[1];
    const int*   tg = (const int*)d_in[2];
    float* ws  = (float*)d_ws;
    float* out = (float*)d_out;

    hipLaunchKernelGGL(crf_phase_kernel, dim3(512), dim3(1024), 0, stream, em, tr, tg, ws);
    hipLaunchKernelGGL(crf_reduce_kernel, dim3(1), dim3(64), 0, stream, ws, out);
}

// Round 9
// 101.444 us; speedup vs baseline: 1.3270x; 1.0555x over previous
//
#include <hip/hip_runtime.h>

#define L2E 1.4426950408889634f
#define LN2 0.6931471805599453f

typedef float f32x16 __attribute__((ext_vector_type(16)));
typedef float f32x2  __attribute__((ext_vector_type(2)));
typedef short bf16x8 __attribute__((ext_vector_type(8)));
typedef unsigned int u32x4 __attribute__((ext_vector_type(4)));

__device__ __forceinline__ float dexp2(float x) { return __builtin_amdgcn_exp2f(x); }
__device__ __forceinline__ float dlog2(float x) { return __builtin_amdgcn_logf(x); }

// HW packed f32->2xbf16 (RNE). Inputs must be IR-produced VALU values
// (never raw MFMA accumulator regs) -- R3 post-mortem.
__device__ __forceinline__ unsigned cvtpk(float a, float b) {
    unsigned r;
    asm("v_cvt_pk_bf16_f32 %0, %1, %2" : "=v"(r) : "v"(a), "v"(b));
    return r;
}

// Software RNE pack (pure IR): for cold paths reading raw MFMA results.
__device__ __forceinline__ unsigned pkrne(float a, float b) {
    unsigned ua = __float_as_uint(a), ub = __float_as_uint(b);
    ua += 0x7FFFu + ((ua >> 16) & 1u);
    ub += 0x7FFFu + ((ub >> 16) & 1u);
    return __builtin_amdgcn_perm(ub, ua, 0x07060302u);
}

// CRF forward via exp-domain transfer matrices, C-form chain:
//   tau_t = E * (D_t * tau_{t-1}),  tau_0 = E[:,START]
// R5-R8 showed the kernel is latency-bound on the per-step chain
// (pk_mul -> cvtpk -> MFMA -> MFMA) with ~3.4 waves/SIMD. This version runs
// TWO independent chains per wave (two batches per WG) so each wave fills
// its own stalls: wave w owns chunk w of batch 2*blockIdx and 2*blockIdx+1.
__global__ __launch_bounds__(1024, 4) void crf_phase_kernel(
    const float* __restrict__ em,   // [512][2048][32]
    const float* __restrict__ tr,   // [32][32] transitions[tag][prev]
    const int*   __restrict__ tgs,  // [512][2048]
    float*       __restrict__ ws)   // [512] per-batch nll
{
    __shared__ float s_tr[1024];                     // 4 KB
    __shared__ unsigned short s_mat[2 * 16 * 1024];  // 64 KB [bk][chunk][col][row]
    __shared__ unsigned s_d8[2 * 16 * 64];           // 8 KB [bk][wave][8 slots][8 dw]
    __shared__ float s_vec[64];                      // phase-2 scratch (2 banks)
    __shared__ float s_base[2][16];
    __shared__ float s_gold[2][16];

    const int tid = threadIdx.x;
    const int b0  = blockIdx.x * 2;
    const int w   = tid >> 6;    // wave = chunk index 0..15
    const int l   = tid & 63;
    const int h   = l >> 5;
    const int q   = l & 31;

    s_tr[tid & 1023] = tr[tid & 1023];
    __syncthreads();

    // Constant A = E with pi'd columns (pi = swap bits 2<->3), bf16, packed once.
    unsigned ea[8];
#pragma unroll
    for (int j = 0; j < 8; ++j) {
        int k0  = 16 * (j >> 2) + 8 * h + 2 * (j & 3);
        int col = (k0 & ~12) | ((k0 & 4) << 1) | ((k0 & 8) >> 1);
        ea[j] = pkrne(dexp2(s_tr[q * 32 + col] * L2E),
                      dexp2(s_tr[q * 32 + col + 1] * L2E));
    }
    const bf16x8 A0 = __builtin_bit_cast(bf16x8, (u32x4){ea[0], ea[1], ea[2], ea[3]});
    const bf16x8 A1 = __builtin_bit_cast(bf16x8, (u32x4){ea[4], ea[5], ea[6], ea[7]});

    f32x16 zro;
#pragma unroll
    for (int z = 0; z < 16; ++z) zro[z] = 0.f;

    const float* ebA = em + ((size_t)b0 * 2048 + (size_t)w * 128) * 32;
    const float* ebB = ebA + (size_t)2048 * 32;
    const int*   tgA = tgs + (size_t)b0 * 2048;
    const int*   tgB = tgA + 2048;

    f32x16 accA, accB;
    float  scA = 1.f, scB = 1.f;
    int    kpA = 0, kpB = 0, sgA = 0, sgB = 0;
    float  goldA = 0.f, goldB = 0.f;
    float4 r0A, r1A, r0B, r1B;
    int    trA = 0, tlA = 0, trB = 0, tlB = 0;   // current 64-group tags
    int    trAn = 0, tlAn = 0, trBn = 0, tlBn = 0;

#pragma unroll
    for (int r = 0; r < 16; ++r) {
        float iv = ((((r & 3) + 8 * (r >> 2) + 4 * h) == q) ? 1.f : 0.f);
        accA[r] = iv; accB[r] = iv;
    }

    auto eload = [&](const float* eb, int blk) -> float4 {
        int bb2 = blk > 15 ? 15 : blk;
        return *(const float4*)(eb + ((bb2 * 8 + (l >> 3)) * 32 + (l & 7) * 4));
    };
    auto tagload = [&](const int* tgp, int cl, int& treg, int& tlast) {
        int c0 = w * 128 + cl * 64;
        int idx = c0 - 1 + l; if (idx < 0) idx = 0;
        treg  = tgp[idx];
        tlast = tgp[c0 + 63];
    };

    r0A = eload(ebA, 0); r1A = eload(ebA, 1);
    r0B = eload(ebB, 0); r1B = eload(ebB, 1);
    tagload(tgA, 0, trA, tlA);
    tagload(tgB, 0, trB, tlB);

#pragma unroll 1
    for (int blk = 0; blk < 16; ++blk) {
        if ((blk & 7) == 0) {
            int cl = blk >> 3;
            int cg = w * 2 + cl;
            if (cl > 0) { trA = trAn; tlA = tlAn; trB = trBn; tlB = tlBn; }
            {   // gold transition terms, both chains
                int sA = __shfl(trA, (l + 1) & 63, 64);
                int cA = (l == 63) ? tlA : sA;
                int pA = trA;
                int sB = __shfl(trB, (l + 1) & 63, 64);
                int cB = (l == 63) ? tlB : sB;
                int pB = trB;
                if (l == 0 && cg == 0) { pA = 30; pB = 30; }   // START
                goldA += s_tr[cA * 32 + pA];
                goldB += s_tr[cB * 32 + pB];
            }
            if (cl < 1) { tagload(tgA, 1, trAn, tlAn); tagload(tgB, 1, trBn, tlBn); }
        }

        // ---- stage d_t = exp(e_t) as fp8 half-permuted; gold pick (both) ----
        {
            int trel = (blk & 7) * 8 + (l >> 3);
            int c = l & 7;
            int slot = w * 64 + (l >> 3) * 8 + (c & 1) * 4 + (c >> 1);
            {
                int tshf = __shfl(trA, (trel + 1) & 63, 64);
                int tgt  = (trel == 63) ? tlA : tshf;
                if ((tgt >> 2) == c) {
                    int sub = tgt & 3;
                    goldA += sub == 0 ? r0A.x : sub == 1 ? r0A.y : sub == 2 ? r0A.z : r0A.w;
                }
                float4 dv;
                dv.x = dexp2(r0A.x * L2E); dv.y = dexp2(r0A.y * L2E);
                dv.z = dexp2(r0A.z * L2E); dv.w = dexp2(r0A.w * L2E);
                unsigned u = (unsigned)__builtin_amdgcn_cvt_pk_fp8_f32(dv.x, dv.y, 0, false);
                u = (unsigned)__builtin_amdgcn_cvt_pk_fp8_f32(dv.z, dv.w, (int)u, true);
                s_d8[slot] = u;
            }
            {
                int tshf = __shfl(trB, (trel + 1) & 63, 64);
                int tgt  = (trel == 63) ? tlB : tshf;
                if ((tgt >> 2) == c) {
                    int sub = tgt & 3;
                    goldB += sub == 0 ? r0B.x : sub == 1 ? r0B.y : sub == 2 ? r0B.z : r0B.w;
                }
                float4 dv;
                dv.x = dexp2(r0B.x * L2E); dv.y = dexp2(r0B.y * L2E);
                dv.z = dexp2(r0B.z * L2E); dv.w = dexp2(r0B.w * L2E);
                unsigned u = (unsigned)__builtin_amdgcn_cvt_pk_fp8_f32(dv.x, dv.y, 0, false);
                u = (unsigned)__builtin_amdgcn_cvt_pk_fp8_f32(dv.z, dv.w, (int)u, true);
                s_d8[1024 + slot] = u;
            }
        }
        r0A = r1A; r1A = eload(ebA, blk + 2);
        r0B = r1B; r1B = eload(ebB, blk + 2);

        const bool skiplast = (blk == 15) && (w == 15);  // each batch's step 2048

        // ---- 8 steps x 2 chains, interleaved for ILP ----
#pragma unroll
        for (int s = 0; s < 8; ++s) {
            if (s == 7 && skiplast) continue;
#define DO_STEP(ACC, SC, KP, SG, BANK) do { \
            const u32x4 rv = *(const u32x4*)(s_d8 + (BANK) + w * 64 + s * 8 + h * 4); \
            unsigned bbn[8]; \
            _Pragma("unroll") for (int q2 = 0; q2 < 4; ++q2) { \
                f32x2 dlo = __builtin_amdgcn_cvt_pk_f32_fp8((int)rv[q2], false); \
                f32x2 dhi = __builtin_amdgcn_cvt_pk_f32_fp8((int)rv[q2], true); \
                f32x2 a0; a0.x = ACC[4 * q2 + 0]; a0.y = ACC[4 * q2 + 1]; \
                f32x2 a1; a1.x = ACC[4 * q2 + 2]; a1.y = ACC[4 * q2 + 3]; \
                f32x2 m0 = a0 * dlo; \
                f32x2 m1 = a1 * dhi; \
                if (s == 0 || s == 4) { \
                    f32x2 sc; sc.x = SC; sc.y = SC; \
                    m0 = m0 * sc; m1 = m1 * sc; \
                } \
                bbn[2 * q2]     = cvtpk(m0.x, m0.y); \
                bbn[2 * q2 + 1] = cvtpk(m1.x, m1.y); \
            } \
            if (s == 0 || s == 4) SG += KP; \
            bf16x8 B0 = __builtin_bit_cast(bf16x8, (u32x4){bbn[0], bbn[1], bbn[2], bbn[3]}); \
            bf16x8 B1 = __builtin_bit_cast(bf16x8, (u32x4){bbn[4], bbn[5], bbn[6], bbn[7]}); \
            f32x16 t = __builtin_amdgcn_mfma_f32_32x32x16_bf16(A0, B0, zro, 0, 0, 0); \
            ACC = __builtin_amdgcn_mfma_f32_32x32x16_bf16(A1, B1, t, 0, 0, 0); \
            if (s == 3 || s == 7) { \
                unsigned eb = (__float_as_uint(ACC[0]) >> 23) & 0xFF; \
                unsigned ku = (unsigned)__builtin_amdgcn_readfirstlane((int)eb); \
                KP = (int)ku - 127; \
                SC = __uint_as_float((254u - ku) << 23); \
            } \
} while (0)
            DO_STEP(accA, scA, kpA, sgA, 0);
            DO_STEP(accB, scB, kpB, sgB, 1024);
#undef DO_STEP
        }
    }

    // ---- store chunk matrices (both chains) ----
#pragma unroll
    for (int p = 0; p < 8; ++p) {
        int rrow = ((2 * p) & 3) + 8 * ((2 * p) >> 2) + 4 * h;
        *(unsigned*)(s_mat + w * 1024 + q * 32 + rrow) = pkrne(accA[2 * p], accA[2 * p + 1]);
        *(unsigned*)(s_mat + 16 * 1024 + w * 1024 + q * 32 + rrow) = pkrne(accB[2 * p], accB[2 * p + 1]);
    }
    if (l == 0) { s_base[0][w] = (float)sgA; s_base[1][w] = (float)sgB; }

    // per-wave gold reductions
#pragma unroll
    for (int m = 1; m < 64; m <<= 1) goldA += __shfl_xor(goldA, m, 64);
#pragma unroll
    for (int m = 1; m < 64; m <<= 1) goldB += __shfl_xor(goldB, m, 64);
    if (l == 0) { s_gold[0][w] = goldA; s_gold[1][w] = goldB; }
    __syncthreads();

    // ---- phase 2: lanes 0..31 chain batch0, lanes 32..63 chain batch1 ----
    if (tid < 64) {
        int h2 = tid >> 5;          // which batch of the pair
        int i  = tid & 31;
        const unsigned short* mat = s_mat + h2 * 16 * 1024;
        const int* tgp = h2 ? tgB : tgA;
        float x  = dexp2(s_tr[i * 32 + 30] * L2E);   // tau_0 = E[:,START]
        float xb = 0.f, bs = 0.f;
        for (int c = 0; c < 16; ++c) {
            s_vec[h2 * 32 + i] = x;
            float yv[32];
#pragma unroll
            for (int j = 0; j < 8; ++j)
                *(float4*)&yv[4 * j] = *(const float4*)&s_vec[h2 * 32 + 4 * j];
            float a2 = 0.f;
#pragma unroll
            for (int j = 0; j < 32; ++j) {
                unsigned short uv = mat[c * 1024 + j * 32 + i];
                a2 += __uint_as_float((unsigned)uv << 16) * yv[j];
            }
            unsigned eb2 = (__float_as_uint(a2) >> 23) & 0xFF;
            int ku0 = __shfl((int)eb2, 0, 32);
            x  = a2 * __uint_as_float((unsigned)(254 - ku0) << 23);
            xb += (float)(ku0 - 127);
            bs += s_base[h2][c];
        }
        // final: Z = sum_i exp(tr[STOP,i] + e_2048[i]) * tau_2047[i]
        float elast = em[((size_t)(b0 + h2) * 2048 + 2047) * 32 + i];
        float wv = dexp2((s_tr[31 * 32 + i] + elast) * L2E);
        float sv = x * wv;
#pragma unroll
        for (int m2 = 1; m2 < 32; m2 <<= 1) sv += __shfl_xor(sv, m2, 32);
        float logZ = (xb + bs + dlog2(sv)) * LN2;
        if (i == 0) {
            float g = 0.f;
#pragma unroll
            for (int wv2 = 0; wv2 < 16; ++wv2) g += s_gold[h2][wv2];
            g += s_tr[31 * 32 + tgp[2047]];   // STOP term
            ws[b0 + h2] = logZ - g;
        }
    }
}

// Deterministic fixed-order reduction of the 512 per-batch values.
__global__ __launch_bounds__(64) void crf_reduce_kernel(
    const float* __restrict__ ws, float* __restrict__ out)
{
    int l = threadIdx.x;
    float s = 0.f;
#pragma unroll
    for (int k = 0; k < 8; ++k) s += ws[l + k * 64];
    s += __shfl_xor(s, 1, 64);
    s += __shfl_xor(s, 2, 64);
    s += __shfl_xor(s, 4, 64);
    s += __shfl_xor(s, 8, 64);
    s += __shfl_xor(s, 16, 64);
    s += __shfl_xor(s, 32, 64);
    if (l == 0) out[0] = s;
}

extern "C" void kernel_launch(void* const* d_in, const int* in_sizes, int n_in,
                              void* d_out, int out_size, void* d_ws, size_t ws_size,
                              hipStream_t stream)
{
    const float* em = (const float*)d_in[0];
    const float* tr = (const float*)d_in[1];
    const int*   tg = (const int*)d_in[2];
    float* ws  = (float*)d_ws;
    float* out = (float*)d_out;

    hipLaunchKernelGGL(crf_phase_kernel, dim3(256), dim3(1024), 0, stream, em, tr, tg, ws);
    hipLaunchKernelGGL(crf_reduce_kernel, dim3(1), dim3(64), 0, stream, ws, out);
}